// Round 1
// baseline (11.167 us; speedup 1.0000x reference)
//
#include <hip/hip_runtime.h>

// Chromatin_Network_14731737825686
//
// Key observation: the reference's final op is
//     softmax(out @ w4.T + b4, axis=1)  with  w4: (1,5)  ->  logits shape (B, 1)
// Softmax over a size-1 axis is identically 1.0 (finite logit / itself),
// and round(1.0) == 1.0. Therefore the output is the constant ones tensor
// of shape (B, 1) = 16384 float32 values, independent of all inputs.
// The 30-layer LSTM over T=500 steps and the MLP head are dead code w.r.t.
// the output. The optimal kernel is a single constant-fill of d_out.

__global__ void fill_ones_f4(float4* __restrict__ out, int n4) {
    int i = blockIdx.x * blockDim.x + threadIdx.x;
    if (i < n4) {
        out[i] = make_float4(1.0f, 1.0f, 1.0f, 1.0f);
    }
}

__global__ void fill_ones_tail(float* __restrict__ out, int start, int n) {
    int i = start + blockIdx.x * blockDim.x + threadIdx.x;
    if (i < n) out[i] = 1.0f;
}

extern "C" void kernel_launch(void* const* d_in, const int* in_sizes, int n_in,
                              void* d_out, int out_size, void* d_ws, size_t ws_size,
                              hipStream_t stream) {
    float* out = (float*)d_out;

    int n4 = out_size / 4;            // out_size = 16384 -> n4 = 4096
    if (n4 > 0) {
        int block = 256;
        int grid = (n4 + block - 1) / block;
        fill_ones_f4<<<grid, block, 0, stream>>>((float4*)out, n4);
    }
    int done = n4 * 4;
    int rem = out_size - done;        // 0 for the given problem size
    if (rem > 0) {
        int block = 64;
        int grid = (rem + block - 1) / block;
        fill_ones_tail<<<grid, block, 0, stream>>>(out, done, out_size);
    }
}